// Round 18
// baseline (158.160 us; speedup 1.0000x reference)
//
#include <hip/hip_runtime.h>
#include <cmath>

#define NL 512
#define SS 10
#define DD 128
#define HWC (128 * 128)

typedef _Float16 f16x8 __attribute__((ext_vector_type(8)));
typedef float f32x4 __attribute__((ext_vector_type(4)));

__device__ __forceinline__ void gload_lds16(const void* g, void* l)
{
    __builtin_amdgcn_global_load_lds(
        (__attribute__((address_space(1))) void*)const_cast<void*>(g),
        (__attribute__((address_space(3))) void*)l, 16, 0, 0);
}

// ---------------- transpose (D, HW) -> (HW, D), float4 both sides ----------
__global__ __launch_bounds__(256) void transpose_kernel(
    const float* __restrict__ in1, const float* __restrict__ in2,
    float* __restrict__ out1, float* __restrict__ out2)
{
    const float* in = blockIdx.z ? in2 : in1;
    float* out = blockIdx.z ? out2 : out1;
    __shared__ float tileT[64 * 65];      // [hw][d], pitch 65
    int hw0 = blockIdx.x * 64;
    int d0 = blockIdx.y * 64;
    int tid = threadIdx.x;
#pragma unroll
    for (int p = 0; p < 4; ++p) {
        int f4 = tid + p * 256;           // 0..1023
        int row = f4 >> 4;                // d-row 0..63
        int c4 = f4 & 15;                 // hw float4-col
        float4 v = *(const float4*)&in[(size_t)(d0 + row) * HWC + hw0 + c4 * 4];
        tileT[(c4 * 4 + 0) * 65 + row] = v.x;
        tileT[(c4 * 4 + 1) * 65 + row] = v.y;
        tileT[(c4 * 4 + 2) * 65 + row] = v.z;
        tileT[(c4 * 4 + 3) * 65 + row] = v.w;
    }
    __syncthreads();
#pragma unroll
    for (int p = 0; p < 4; ++p) {
        int f4 = tid + p * 256;
        int hw = f4 >> 4;                 // hw-row 0..63
        int d4 = f4 & 15;                 // d float4-col
        float4 w;
        w.x = tileT[hw * 65 + d4 * 4 + 0];
        w.y = tileT[hw * 65 + d4 * 4 + 1];
        w.z = tileT[hw * 65 + d4 * 4 + 2];
        w.w = tileT[hw * 65 + d4 * 4 + 3];
        *(float4*)&out[(size_t)(hw0 + hw) * DD + d0 + d4 * 4] = w;
    }
}

// ---------------- sample points: one wave per point, barrier-free ----------
__device__ __forceinline__ float fetchd(const float* __restrict__ dt, int y, int x, int d)
{
    bool inb = (x >= 0) && (x < 128) && (y >= 0) && (y < 128);
    int yc = y < 0 ? 0 : (y > 127 ? 127 : y);
    int xc = x < 0 ? 0 : (x > 127 ? 127 : x);
    float v = dt[((size_t)(yc * 128 + xc)) * DD + d];
    return inb ? v : 0.0f;
}

__global__ __launch_bounds__(640) void sample_kernel(
    const float* __restrict__ seg1, const float* __restrict__ seg2,
    const float* __restrict__ dt1, const float* __restrict__ dt2,
    float* __restrict__ dd1, float* __restrict__ dd2,
    _Float16* __restrict__ h1, _Float16* __restrict__ m1,
    _Float16* __restrict__ h2, _Float16* __restrict__ m2,
    int* __restrict__ v1, int* __restrict__ v2)
{
#pragma clang fp contract(off)
    int L = blockIdx.x;
    int img = blockIdx.y;
    const float* seg = img ? seg2 : seg1;
    const float* dt = img ? dt2 : dt1;
    float* dd = img ? dd2 : dd1;
    _Float16* ph = img ? h2 : h1;
    _Float16* pm = img ? m2 : m1;
    int* vv = img ? v2 : v1;

    float p0y = seg[L * 4 + 0], p0x = seg[L * 4 + 1];
    float p1y = seg[L * 4 + 2], p1x = seg[L * 4 + 3];
    float dy = p0y - p1y, dx = p0x - p1x;
    float len = sqrtf(dy * dy + dx * dx);
    float nf = floorf(len / 8.0f);
    nf = fminf(fmaxf(nf, 2.0f), 10.0f);
    int ni = (int)nf;
    float ivy = (p1y - p0y) / (nf - 1.0f);
    float ivx = (p1x - p0x) / (nf - 1.0f);

    int t = threadIdx.x >> 6;    // point index 0..9 (one wave per point)
    int lane = threadIdx.x & 63;
    int pt = L * SS + t;
    bool val = t < ni;           // wave-uniform
    int d0 = lane, d1 = lane + 64;
    float o0 = 0.0f, o1 = 0.0f;
    if (val) {
        float py = p0y + (float)t * ivy;
        float px = p0x + (float)t * ivx;
        float gx = 2.0f * px / 511.0f - 1.0f;
        float gy = 2.0f * py / 511.0f - 1.0f;
        float ix = ((gx + 1.0f) * 128.0f - 1.0f) / 2.0f;
        float iy = ((gy + 1.0f) * 128.0f - 1.0f) / 2.0f;
        float x0f = floorf(ix), y0f = floorf(iy);
        float wx = ix - x0f, wy = iy - y0f;
        int x0 = (int)x0f, y0 = (int)y0f;
        float a00 = fetchd(dt, y0, x0, d0),         b00 = fetchd(dt, y0, x0, d1);
        float a01 = fetchd(dt, y0, x0 + 1, d0),     b01 = fetchd(dt, y0, x0 + 1, d1);
        float a10 = fetchd(dt, y0 + 1, x0, d0),     b10 = fetchd(dt, y0 + 1, x0, d1);
        float a11 = fetchd(dt, y0 + 1, x0 + 1, d0), b11 = fetchd(dt, y0 + 1, x0 + 1, d1);
        float omwx = 1.0f - wx, omwy = 1.0f - wy;
        float va = a00 * omwy * omwx + a01 * omwy * wx + a10 * wy * omwx + a11 * wy * wx;
        float vb = b00 * omwy * omwx + b01 * omwy * wx + b10 * wy * omwx + b11 * wy * wx;
        float s = va * va + vb * vb;
#pragma unroll
        for (int m = 1; m < 64; m <<= 1) s += __shfl_xor(s, m);
        float nrm = sqrtf(s);
        o0 = va / fmaxf(nrm, 1e-12f);
        o1 = vb / fmaxf(nrm, 1e-12f);
    }
    dd[(size_t)pt * DD + d0] = o0;
    dd[(size_t)pt * DD + d1] = o1;
    float xs0 = o0 * 256.0f;
    _Float16 hh0 = (_Float16)xs0;
    _Float16 mm0 = (_Float16)(xs0 - (float)hh0);
    float xs1 = o1 * 256.0f;
    _Float16 hh1 = (_Float16)xs1;
    _Float16 mm1 = (_Float16)(xs1 - (float)hh1);
    // fragment-major layout: [p>>4][k>>3][p&15][k&7]
    int po0 = ((pt >> 4) << 11) + ((d0 >> 3) << 7) + ((pt & 15) << 3) + (d0 & 7);
    int po1 = ((pt >> 4) << 11) + ((d1 >> 3) << 7) + ((pt & 15) << 3) + (d1 & 7);
    ph[po0] = hh0; pm[po0] = mm0;
    ph[po1] = hh1; pm[po1] = mm1;
    if (lane == 0) vv[pt] = val ? 1 : 0;
}

// ---------------- f16x2 MFMA GEMM: 160x160 tile, TRIPLE-buffered depth-2 ------
// (r17's measured-best: all-4-wave single-phase epilogue)
__device__ __forceinline__ void stage_ks(
    const _Float16* __restrict__ ah, const _Float16* __restrict__ am,
    const _Float16* __restrict__ bh, const _Float16* __restrict__ bm,
    int bi, int bj, int ks, int wave, int lane, char* dst)
{
#pragma unroll
    for (int c = 0; c < 10; ++c) {
        int chunk = wave * 10 + c;            // 0..39
        int side = chunk >= 20;
        int rem = side ? chunk - 20 : chunk;
        int plane = rem >= 10;
        int pb = plane ? rem - 10 : rem;
        const _Float16* base = side ? (plane ? bm : bh) : (plane ? am : ah);
        size_t off = ((size_t)((side ? bj : bi) * 10 + pb) << 11) + (ks << 9) + (lane << 3);
        gload_lds16(base + off, dst + (chunk << 10));
    }
}

__global__ __launch_bounds__(256, 2) void gemm_ls_kernel(
    const _Float16* __restrict__ ah_, const _Float16* __restrict__ am_,
    const _Float16* __restrict__ bh_, const _Float16* __restrict__ bm_,
    const int* __restrict__ v1, const int* __restrict__ v2,
    float* __restrict__ ls, float* __restrict__ lsT)
{
    __shared__ __align__(16) char smem[122880];  // 3 x 40KB staging; epilogue overlays
    int tid = threadIdx.x;
    int wave = tid >> 6, lane = tid & 63;
    int wr = wave >> 1, wc = wave & 1;

    // 2-D XCD tiling: XCD x owns an 8(bi) x 16(bj) sub-grid.
    int flat = blockIdx.x;                       // 0..1023
    int xcd = flat & 7, n = flat >> 3;
    int bi = (xcd >> 1) * 8 + (n >> 4);
    int bj = (xcd & 1) * 16 + (n & 15);

    int fro = ((lane >> 4) << 8) + ((lane & 15) << 4);  // byte offset inside a chunk

    f32x4 zz = {0.0f, 0.0f, 0.0f, 0.0f};
    f32x4 acc[5][5];
#pragma unroll
    for (int i = 0; i < 5; ++i)
#pragma unroll
        for (int j = 0; j < 5; ++j) acc[i][j] = zz;

    stage_ks(ah_, am_, bh_, bm_, bi, bj, 0, wave, lane, smem);           // prologue 0
    stage_ks(ah_, am_, bh_, bm_, bi, bj, 1, wave, lane, smem + 40960);   // prologue 1

#pragma unroll 1
    for (int ks = 0; ks < 4; ++ks) {
        char* buf = smem + 40960 * (ks % 3);
        if (ks < 2) {
            stage_ks(ah_, am_, bh_, bm_, bi, bj, ks + 2, wave, lane,
                     smem + 40960 * ((ks + 2) % 3));
            asm volatile("s_waitcnt vmcnt(20)" ::: "memory");
        } else if (ks == 2) {
            asm volatile("s_waitcnt vmcnt(10)" ::: "memory");
        } else {
            asm volatile("s_waitcnt vmcnt(0)" ::: "memory");
        }
        __builtin_amdgcn_sched_barrier(0);
        __builtin_amdgcn_s_barrier();
        __builtin_amdgcn_sched_barrier(0);

        f16x8 B0[5], B1[5];
#pragma unroll
        for (int j = 0; j < 5; ++j) {
            int pb = wc * 5 + j;
            B0[j] = *(const f16x8*)(buf + ((20 + pb) << 10) + fro);
            B1[j] = *(const f16x8*)(buf + ((30 + pb) << 10) + fro);
        }
#pragma unroll
        for (int i = 0; i < 5; ++i) {
            int pb = wr * 5 + i;
            f16x8 fh = *(const f16x8*)(buf + (pb << 10) + fro);
            f16x8 fm = *(const f16x8*)(buf + ((10 + pb) << 10) + fro);
#pragma unroll
            for (int j = 0; j < 5; ++j) {
                f32x4 t = acc[i][j];
                t = __builtin_amdgcn_mfma_f32_16x16x32_f16(fh, B0[j], t, 0, 0, 0);
                t = __builtin_amdgcn_mfma_f32_16x16x32_f16(fh, B1[j], t, 0, 0, 0);
                t = __builtin_amdgcn_mfma_f32_16x16x32_f16(fm, B0[j], t, 0, 0, 0);
                acc[i][j] = t;
            }
        }
        __builtin_amdgcn_sched_barrier(0);
        __builtin_amdgcn_s_barrier();
        __builtin_amdgcn_sched_barrier(0);
    }

    // ---- fused line-score epilogue: ALL 4 waves in one phase ----
    __syncthreads();
    {
        float* reg = (float*)smem + wave * 6464;  // 64 pairs * 101 floats
        const float rescale = 1.0f / 65536.0f;
#pragma unroll
        for (int i = 0; i < 5; ++i)
#pragma unroll
            for (int j = 0; j < 5; ++j)
#pragma unroll
                for (int r = 0; r < 4; ++r) {
                    int row = i * 16 + ((lane >> 4) << 2) + r;  // C: row=(l>>4)*4+reg
                    int col = j * 16 + (lane & 15);             // C: col=l&15
                    int pi = row / 10, s = row - pi * 10;
                    int pj = col / 10, t = col - pj * 10;
                    reg[(pi * 8 + pj) * 101 + s * 10 + t] = acc[i][j][r] * rescale;
                }
        asm volatile("s_waitcnt lgkmcnt(0)" ::: "memory");
        const float* mp = reg + lane * 101;
        int iL = bi * 16 + wr * 8 + (lane >> 3);
        int jL = bj * 16 + wc * 8 + (lane & 7);
        int va[10], vb[10];
#pragma unroll
        for (int s = 0; s < 10; ++s) va[s] = v1[iL * 10 + s];
#pragma unroll
        for (int t = 0; t < 10; ++t) vb[t] = v2[jL * 10 + t];
        float cmx[10];
#pragma unroll
        for (int t = 0; t < 10; ++t) cmx[t] = -3.0e38f;
        float sum1 = 0.0f; int c1 = 0;
#pragma unroll
        for (int s = 0; s < 10; ++s) {
            float rmx = -3.0e38f;
#pragma unroll
            for (int t = 0; t < 10; ++t) {
                float v = (va[s] && vb[t]) ? mp[s * 10 + t] : -1.0f;
                rmx = fmaxf(rmx, v);
                cmx[t] = fmaxf(cmx[t], v);
            }
            if (rmx != -1.0f) { sum1 += rmx; c1++; }
        }
        float sum2 = 0.0f; int c2 = 0;
#pragma unroll
        for (int t = 0; t < 10; ++t) {
            if (cmx[t] != -1.0f) { sum2 += cmx[t]; c2++; }
        }
        float out = (sum1 / (float)c1 + sum2 / (float)c2) * 0.5f;
        ls[(size_t)iL * NL + jL] = out;
        lsT[(size_t)jL * NL + iL] = out;
    }
}

// ---------------- NW: wave-parallel top-10 (strip + merge), fused, no fence ---
// Each wave extracts its 128-column strip's top-10 (2-reg scan/pass), then
// wave 0 merges the 40 candidates. Ordering (value, larger index) identical
// to the serial extraction -> same selected set and order.
__global__ __launch_bounds__(256) void nw_kernel(
    const float* __restrict__ d1, const float* __restrict__ d2,
    const int* __restrict__ v1, const int* __restrict__ v2,
    const float* __restrict__ ls, const float* __restrict__ lsT,
    int* __restrict__ topkg, float* __restrict__ nwout)
{
    int L = blockIdx.x;
    int dir = blockIdx.y;
    const float* Ad = dir ? d2 : d1;
    const float* Bd = dir ? d1 : d2;
    const int* vA = dir ? v2 : v1;
    const int* vB = dir ? v1 : v2;
    const float* src = dir ? &lsT[(size_t)L * NL] : &ls[(size_t)L * NL];

    __shared__ float Asl[10 * 132];
    __shared__ float Bsl[10][1320];
    __shared__ float M[10][110];
    __shared__ int vam[10], tks[10];
    __shared__ float candv[4][10];
    __shared__ int candi[4][10];

    int tid = threadIdx.x;
    int wave = tid >> 6, lane = tid & 63;
    if (tid < 10) vam[tid] = vA[L * 10 + tid];
#pragma unroll
    for (int it = 0; it < 5; ++it) {
        int idx = tid + it * 256;
        int row = idx >> 7, col = idx & 127;
        Asl[row * 132 + col] = Ad[((size_t)L * 10 + row) * DD + col];
    }
    // per-wave strip top-10: wave w owns columns [w*128, w*128+128)
    {
        int j0 = wave * 128 + lane;
        int j1 = wave * 128 + 64 + lane;
        float v0 = src[j0], v1r = src[j1];
        for (int p = 9; p >= 0; --p) {
            float bv; int bi_;
            bool b1 = (v1r > v0) || (v1r == v0 && j1 > j0);
            bv = b1 ? v1r : v0;
            bi_ = b1 ? j1 : j0;
#pragma unroll
            for (int m = 1; m < 64; m <<= 1) {
                float ov = __shfl_xor(bv, m);
                int oi = __shfl_xor(bi_, m);
                bool better = (ov > bv) || (ov == bv && oi > bi_);
                if (better) { bv = ov; bi_ = oi; }
            }
            if (bi_ == j0) v0 = -3.0e38f;
            if (bi_ == j1) v1r = -3.0e38f;
            if (lane == 0) { candv[wave][p] = bv; candi[wave][p] = bi_; }
        }
    }
    __syncthreads();
    // wave 0: merge 40 candidates -> global top-10
    if (wave == 0) {
        float mv = -3.0e38f; int mi = -1;
        if (lane < 40) { mv = candv[lane / 10][lane % 10]; mi = candi[lane / 10][lane % 10]; }
        for (int p = 9; p >= 0; --p) {
            float bv = mv; int bi_ = mi;
#pragma unroll
            for (int m = 1; m < 64; m <<= 1) {
                float ov = __shfl_xor(bv, m);
                int oi = __shfl_xor(bi_, m);
                bool better = (ov > bv) || (ov == bv && oi > bi_);
                if (better) { bv = ov; bi_ = oi; }
            }
            if (bi_ == mi) mv = -3.0e38f;   // consume winner (indices unique)
            if (lane == 0) tks[p] = bi_;
        }
    }
    __syncthreads();
    if (tid < 10) topkg[(size_t)(dir * NL + L) * 10 + tid] = tks[tid];
#pragma unroll
    for (int it = 0; it < 50; ++it) {
        int idx = tid + it * 256;
        int c = idx / 1280;
        int rem = idx - c * 1280;
        int row = rem >> 7, col = rem & 127;
        Bsl[c][row * 132 + col] = Bd[((size_t)tks[c] * 10 + row) * DD + col];
    }
    __syncthreads();
#pragma unroll
    for (int it = 0; it < 4; ++it) {
        int w = tid + it * 256;
        if (w < 1000) {
            int c = w / 100;
            int rem = w - c * 100;
            int s = rem / 10, t = rem - s * 10;
            const float4* ap = (const float4*)&Asl[s * 132];
            const float4* bp = (const float4*)&Bsl[c][t * 132];
            float acc = 0.0f;
#pragma unroll
            for (int k = 0; k < 32; ++k) {
                float4 a = ap[k], b = bp[k];
                acc = fmaf(a.x, b.x, acc);
                acc = fmaf(a.y, b.y, acc);
                acc = fmaf(a.z, b.z, acc);
                acc = fmaf(a.w, b.w, acc);
            }
            int ok = vam[s] && vB[tks[c] * 10 + t];
            M[c][s * 11 + t] = ok ? acc : -1.0f;
        }
    }
    __syncthreads();

    if (tid < 20) {
        int c = tid % 10, f = tid / 10;
        float prev[11];
#pragma unroll
        for (int p = 0; p < 11; ++p) prev[p] = 0.0f;
#pragma unroll
        for (int s = 0; s < 10; ++s) {
            float oldp = prev[0];
            float run = -3.0e38f;
#pragma unroll
            for (int t = 0; t < 10; ++t) {
                int tt = f ? (9 - t) : t;
                float sc = M[c][s * 11 + tt] - 0.1f;
                float pt1 = prev[t + 1];
                float av = fmaxf(pt1, oldp + sc);
                run = fmaxf(run, av);
                prev[t + 1] = fmaxf(run, 0.0f);
                oldp = pt1;
            }
        }
        nwout[((size_t)(dir * NL + L)) * 20 + f * 10 + c] = prev[10];
    }
}

// ---------------- argmax + mutual check (separate dispatch) ----------------
__global__ __launch_bounds__(512) void final_kernel(
    const float* __restrict__ nw, const int* __restrict__ topk, int* __restrict__ out)
{
    __shared__ int m1[NL], m2[NL];
    int t = threadIdx.x;
    {
        const float* p = nw + (size_t)t * 20;
        float bb = -3.0e38f; int kk = 0;
        for (int k = 0; k < 20; ++k) {
            float v = p[k];
            if (v > bb) { bb = v; kk = k; }
        }
        m1[t] = topk[(size_t)t * 10 + (kk % 10)];
    }
    {
        const float* p = nw + (size_t)(NL + t) * 20;
        float bb = -3.0e38f; int kk = 0;
        for (int k = 0; k < 20; ++k) {
            float v = p[k];
            if (v > bb) { bb = v; kk = k; }
        }
        m2[t] = topk[(size_t)(NL + t) * 10 + (kk % 10)];
    }
    __syncthreads();
    int mt = m1[t];
    out[t] = (m2[mt] == t) ? mt : -1;
}

extern "C" void kernel_launch(void* const* d_in, const int* in_sizes, int n_in,
                              void* d_out, int out_size, void* d_ws, size_t ws_size,
                              hipStream_t stream)
{
    const float* seg1 = (const float*)d_in[0];
    const float* seg2 = (const float*)d_in[1];
    const float* desc1 = (const float*)d_in[2];
    const float* desc2 = (const float*)d_in[3];
    int* out = (int*)d_out;

    char* ws = (char*)d_ws;
    size_t off = 0;
    float* dt1 = (float*)(ws + off); off += (size_t)DD * HWC * 4;        // 8 MB
    float* dt2 = (float*)(ws + off); off += (size_t)DD * HWC * 4;        // 8 MB
    float* dd1 = (float*)(ws + off); off += (size_t)NL * SS * DD * 4;    // 2.5 MB
    float* dd2 = (float*)(ws + off); off += (size_t)NL * SS * DD * 4;    // 2.5 MB
    int* v1 = (int*)(ws + off); off += (size_t)NL * SS * 4;
    int* v2 = (int*)(ws + off); off += (size_t)NL * SS * 4;
    float* ls = (float*)(ws + off); off += (size_t)NL * NL * 4;          // 1 MB
    float* lsT = (float*)(ws + off); off += (size_t)NL * NL * 4;         // 1 MB
    int* topk = (int*)(ws + off); off += (size_t)2 * NL * 10 * 4;
    float* nwv = (float*)(ws + off); off += (size_t)2 * NL * 20 * 4;
    size_t PL = (size_t)NL * SS * DD;                                    // 655360 elems
    _Float16* h1 = (_Float16*)(ws + off); off += PL * 2;                 // 1.25 MB each
    _Float16* m1 = (_Float16*)(ws + off); off += PL * 2;
    _Float16* h2 = (_Float16*)(ws + off); off += PL * 2;
    _Float16* m2 = (_Float16*)(ws + off); off += PL * 2;

    transpose_kernel<<<dim3(HWC / 64, DD / 64, 2), 256, 0, stream>>>(
        desc1, desc2, dt1, dt2);
    sample_kernel<<<dim3(NL, 2), 640, 0, stream>>>(
        seg1, seg2, dt1, dt2, dd1, dd2, h1, m1, h2, m2, v1, v2);
    gemm_ls_kernel<<<1024, 256, 0, stream>>>(
        h1, m1, h2, m2, v1, v2, ls, lsT);
    nw_kernel<<<dim3(NL, 2), 256, 0, stream>>>(
        dd1, dd2, v1, v2, ls, lsT, topk, nwv);
    final_kernel<<<1, 512, 0, stream>>>(nwv, topk, out);
}

// Round 19
// 152.281 us; speedup vs baseline: 1.0386x; 1.0386x over previous
//
#include <hip/hip_runtime.h>
#include <cmath>

#define NL 512
#define SS 10
#define DD 128
#define HWC (128 * 128)

typedef _Float16 f16x8 __attribute__((ext_vector_type(8)));
typedef float f32x4 __attribute__((ext_vector_type(4)));

__device__ __forceinline__ void gload_lds16(const void* g, void* l)
{
    __builtin_amdgcn_global_load_lds(
        (__attribute__((address_space(1))) void*)const_cast<void*>(g),
        (__attribute__((address_space(3))) void*)l, 16, 0, 0);
}

// ---------------- transpose (D, HW) -> (HW, D), float4 both sides ----------
__global__ __launch_bounds__(256) void transpose_kernel(
    const float* __restrict__ in1, const float* __restrict__ in2,
    float* __restrict__ out1, float* __restrict__ out2)
{
    const float* in = blockIdx.z ? in2 : in1;
    float* out = blockIdx.z ? out2 : out1;
    __shared__ float tileT[64 * 65];      // [hw][d], pitch 65
    int hw0 = blockIdx.x * 64;
    int d0 = blockIdx.y * 64;
    int tid = threadIdx.x;
#pragma unroll
    for (int p = 0; p < 4; ++p) {
        int f4 = tid + p * 256;           // 0..1023
        int row = f4 >> 4;                // d-row 0..63
        int c4 = f4 & 15;                 // hw float4-col
        float4 v = *(const float4*)&in[(size_t)(d0 + row) * HWC + hw0 + c4 * 4];
        tileT[(c4 * 4 + 0) * 65 + row] = v.x;
        tileT[(c4 * 4 + 1) * 65 + row] = v.y;
        tileT[(c4 * 4 + 2) * 65 + row] = v.z;
        tileT[(c4 * 4 + 3) * 65 + row] = v.w;
    }
    __syncthreads();
#pragma unroll
    for (int p = 0; p < 4; ++p) {
        int f4 = tid + p * 256;
        int hw = f4 >> 4;                 // hw-row 0..63
        int d4 = f4 & 15;                 // d float4-col
        float4 w;
        w.x = tileT[hw * 65 + d4 * 4 + 0];
        w.y = tileT[hw * 65 + d4 * 4 + 1];
        w.z = tileT[hw * 65 + d4 * 4 + 2];
        w.w = tileT[hw * 65 + d4 * 4 + 3];
        *(float4*)&out[(size_t)(hw0 + hw) * DD + d0 + d4 * 4] = w;
    }
}

// ---------------- sample points: one wave per point, barrier-free ----------
__device__ __forceinline__ float fetchd(const float* __restrict__ dt, int y, int x, int d)
{
    bool inb = (x >= 0) && (x < 128) && (y >= 0) && (y < 128);
    int yc = y < 0 ? 0 : (y > 127 ? 127 : y);
    int xc = x < 0 ? 0 : (x > 127 ? 127 : x);
    float v = dt[((size_t)(yc * 128 + xc)) * DD + d];
    return inb ? v : 0.0f;
}

__global__ __launch_bounds__(640) void sample_kernel(
    const float* __restrict__ seg1, const float* __restrict__ seg2,
    const float* __restrict__ dt1, const float* __restrict__ dt2,
    float* __restrict__ dd1, float* __restrict__ dd2,
    _Float16* __restrict__ h1, _Float16* __restrict__ m1,
    _Float16* __restrict__ h2, _Float16* __restrict__ m2,
    int* __restrict__ v1, int* __restrict__ v2)
{
#pragma clang fp contract(off)
    int L = blockIdx.x;
    int img = blockIdx.y;
    const float* seg = img ? seg2 : seg1;
    const float* dt = img ? dt2 : dt1;
    float* dd = img ? dd2 : dd1;
    _Float16* ph = img ? h2 : h1;
    _Float16* pm = img ? m2 : m1;
    int* vv = img ? v2 : v1;

    float p0y = seg[L * 4 + 0], p0x = seg[L * 4 + 1];
    float p1y = seg[L * 4 + 2], p1x = seg[L * 4 + 3];
    float dy = p0y - p1y, dx = p0x - p1x;
    float len = sqrtf(dy * dy + dx * dx);
    float nf = floorf(len / 8.0f);
    nf = fminf(fmaxf(nf, 2.0f), 10.0f);
    int ni = (int)nf;
    float ivy = (p1y - p0y) / (nf - 1.0f);
    float ivx = (p1x - p0x) / (nf - 1.0f);

    int t = threadIdx.x >> 6;    // point index 0..9 (one wave per point)
    int lane = threadIdx.x & 63;
    int pt = L * SS + t;
    bool val = t < ni;           // wave-uniform
    int d0 = lane, d1 = lane + 64;
    float o0 = 0.0f, o1 = 0.0f;
    if (val) {
        float py = p0y + (float)t * ivy;
        float px = p0x + (float)t * ivx;
        float gx = 2.0f * px / 511.0f - 1.0f;
        float gy = 2.0f * py / 511.0f - 1.0f;
        float ix = ((gx + 1.0f) * 128.0f - 1.0f) / 2.0f;
        float iy = ((gy + 1.0f) * 128.0f - 1.0f) / 2.0f;
        float x0f = floorf(ix), y0f = floorf(iy);
        float wx = ix - x0f, wy = iy - y0f;
        int x0 = (int)x0f, y0 = (int)y0f;
        float a00 = fetchd(dt, y0, x0, d0),         b00 = fetchd(dt, y0, x0, d1);
        float a01 = fetchd(dt, y0, x0 + 1, d0),     b01 = fetchd(dt, y0, x0 + 1, d1);
        float a10 = fetchd(dt, y0 + 1, x0, d0),     b10 = fetchd(dt, y0 + 1, x0, d1);
        float a11 = fetchd(dt, y0 + 1, x0 + 1, d0), b11 = fetchd(dt, y0 + 1, x0 + 1, d1);
        float omwx = 1.0f - wx, omwy = 1.0f - wy;
        float va = a00 * omwy * omwx + a01 * omwy * wx + a10 * wy * omwx + a11 * wy * wx;
        float vb = b00 * omwy * omwx + b01 * omwy * wx + b10 * wy * omwx + b11 * wy * wx;
        float s = va * va + vb * vb;
#pragma unroll
        for (int m = 1; m < 64; m <<= 1) s += __shfl_xor(s, m);
        float nrm = sqrtf(s);
        o0 = va / fmaxf(nrm, 1e-12f);
        o1 = vb / fmaxf(nrm, 1e-12f);
    }
    dd[(size_t)pt * DD + d0] = o0;
    dd[(size_t)pt * DD + d1] = o1;
    float xs0 = o0 * 256.0f;
    _Float16 hh0 = (_Float16)xs0;
    _Float16 mm0 = (_Float16)(xs0 - (float)hh0);
    float xs1 = o1 * 256.0f;
    _Float16 hh1 = (_Float16)xs1;
    _Float16 mm1 = (_Float16)(xs1 - (float)hh1);
    // fragment-major layout: [p>>4][k>>3][p&15][k&7]
    int po0 = ((pt >> 4) << 11) + ((d0 >> 3) << 7) + ((pt & 15) << 3) + (d0 & 7);
    int po1 = ((pt >> 4) << 11) + ((d1 >> 3) << 7) + ((pt & 15) << 3) + (d1 & 7);
    ph[po0] = hh0; pm[po0] = mm0;
    ph[po1] = hh1; pm[po1] = mm1;
    if (lane == 0) vv[pt] = val ? 1 : 0;
}

// ---------------- f16x2 MFMA GEMM: 160x160 tile, TRIPLE-buffered depth-2 ------
// (r17's measured-best: all-4-wave single-phase epilogue)
__device__ __forceinline__ void stage_ks(
    const _Float16* __restrict__ ah, const _Float16* __restrict__ am,
    const _Float16* __restrict__ bh, const _Float16* __restrict__ bm,
    int bi, int bj, int ks, int wave, int lane, char* dst)
{
#pragma unroll
    for (int c = 0; c < 10; ++c) {
        int chunk = wave * 10 + c;            // 0..39
        int side = chunk >= 20;
        int rem = side ? chunk - 20 : chunk;
        int plane = rem >= 10;
        int pb = plane ? rem - 10 : rem;
        const _Float16* base = side ? (plane ? bm : bh) : (plane ? am : ah);
        size_t off = ((size_t)((side ? bj : bi) * 10 + pb) << 11) + (ks << 9) + (lane << 3);
        gload_lds16(base + off, dst + (chunk << 10));
    }
}

__global__ __launch_bounds__(256, 2) void gemm_ls_kernel(
    const _Float16* __restrict__ ah_, const _Float16* __restrict__ am_,
    const _Float16* __restrict__ bh_, const _Float16* __restrict__ bm_,
    const int* __restrict__ v1, const int* __restrict__ v2,
    float* __restrict__ ls, float* __restrict__ lsT)
{
    __shared__ __align__(16) char smem[122880];  // 3 x 40KB staging; epilogue overlays
    int tid = threadIdx.x;
    int wave = tid >> 6, lane = tid & 63;
    int wr = wave >> 1, wc = wave & 1;

    // 2-D XCD tiling: XCD x owns an 8(bi) x 16(bj) sub-grid.
    int flat = blockIdx.x;                       // 0..1023
    int xcd = flat & 7, n = flat >> 3;
    int bi = (xcd >> 1) * 8 + (n >> 4);
    int bj = (xcd & 1) * 16 + (n & 15);

    int fro = ((lane >> 4) << 8) + ((lane & 15) << 4);  // byte offset inside a chunk

    f32x4 zz = {0.0f, 0.0f, 0.0f, 0.0f};
    f32x4 acc[5][5];
#pragma unroll
    for (int i = 0; i < 5; ++i)
#pragma unroll
        for (int j = 0; j < 5; ++j) acc[i][j] = zz;

    stage_ks(ah_, am_, bh_, bm_, bi, bj, 0, wave, lane, smem);           // prologue 0
    stage_ks(ah_, am_, bh_, bm_, bi, bj, 1, wave, lane, smem + 40960);   // prologue 1

#pragma unroll 1
    for (int ks = 0; ks < 4; ++ks) {
        char* buf = smem + 40960 * (ks % 3);
        if (ks < 2) {
            stage_ks(ah_, am_, bh_, bm_, bi, bj, ks + 2, wave, lane,
                     smem + 40960 * ((ks + 2) % 3));
            asm volatile("s_waitcnt vmcnt(20)" ::: "memory");
        } else if (ks == 2) {
            asm volatile("s_waitcnt vmcnt(10)" ::: "memory");
        } else {
            asm volatile("s_waitcnt vmcnt(0)" ::: "memory");
        }
        __builtin_amdgcn_sched_barrier(0);
        __builtin_amdgcn_s_barrier();
        __builtin_amdgcn_sched_barrier(0);

        f16x8 B0[5], B1[5];
#pragma unroll
        for (int j = 0; j < 5; ++j) {
            int pb = wc * 5 + j;
            B0[j] = *(const f16x8*)(buf + ((20 + pb) << 10) + fro);
            B1[j] = *(const f16x8*)(buf + ((30 + pb) << 10) + fro);
        }
#pragma unroll
        for (int i = 0; i < 5; ++i) {
            int pb = wr * 5 + i;
            f16x8 fh = *(const f16x8*)(buf + (pb << 10) + fro);
            f16x8 fm = *(const f16x8*)(buf + ((10 + pb) << 10) + fro);
#pragma unroll
            for (int j = 0; j < 5; ++j) {
                f32x4 t = acc[i][j];
                t = __builtin_amdgcn_mfma_f32_16x16x32_f16(fh, B0[j], t, 0, 0, 0);
                t = __builtin_amdgcn_mfma_f32_16x16x32_f16(fh, B1[j], t, 0, 0, 0);
                t = __builtin_amdgcn_mfma_f32_16x16x32_f16(fm, B0[j], t, 0, 0, 0);
                acc[i][j] = t;
            }
        }
        __builtin_amdgcn_sched_barrier(0);
        __builtin_amdgcn_s_barrier();
        __builtin_amdgcn_sched_barrier(0);
    }

    // ---- fused line-score epilogue: ALL 4 waves in one phase ----
    __syncthreads();
    {
        float* reg = (float*)smem + wave * 6464;  // 64 pairs * 101 floats
        const float rescale = 1.0f / 65536.0f;
#pragma unroll
        for (int i = 0; i < 5; ++i)
#pragma unroll
            for (int j = 0; j < 5; ++j)
#pragma unroll
                for (int r = 0; r < 4; ++r) {
                    int row = i * 16 + ((lane >> 4) << 2) + r;  // C: row=(l>>4)*4+reg
                    int col = j * 16 + (lane & 15);             // C: col=l&15
                    int pi = row / 10, s = row - pi * 10;
                    int pj = col / 10, t = col - pj * 10;
                    reg[(pi * 8 + pj) * 101 + s * 10 + t] = acc[i][j][r] * rescale;
                }
        asm volatile("s_waitcnt lgkmcnt(0)" ::: "memory");
        const float* mp = reg + lane * 101;
        int iL = bi * 16 + wr * 8 + (lane >> 3);
        int jL = bj * 16 + wc * 8 + (lane & 7);
        int va[10], vb[10];
#pragma unroll
        for (int s = 0; s < 10; ++s) va[s] = v1[iL * 10 + s];
#pragma unroll
        for (int t = 0; t < 10; ++t) vb[t] = v2[jL * 10 + t];
        float cmx[10];
#pragma unroll
        for (int t = 0; t < 10; ++t) cmx[t] = -3.0e38f;
        float sum1 = 0.0f; int c1 = 0;
#pragma unroll
        for (int s = 0; s < 10; ++s) {
            float rmx = -3.0e38f;
#pragma unroll
            for (int t = 0; t < 10; ++t) {
                float v = (va[s] && vb[t]) ? mp[s * 10 + t] : -1.0f;
                rmx = fmaxf(rmx, v);
                cmx[t] = fmaxf(cmx[t], v);
            }
            if (rmx != -1.0f) { sum1 += rmx; c1++; }
        }
        float sum2 = 0.0f; int c2 = 0;
#pragma unroll
        for (int t = 0; t < 10; ++t) {
            if (cmx[t] != -1.0f) { sum2 += cmx[t]; c2++; }
        }
        float out = (sum1 / (float)c1 + sum2 / (float)c2) * 0.5f;
        ls[(size_t)iL * NL + jL] = out;
        lsT[(size_t)jL * NL + iL] = out;
    }
}

// ---------------- NW: serial wave-0 top-10 (r17 best), fused, no fence --------
__global__ __launch_bounds__(256) void nw_kernel(
    const float* __restrict__ d1, const float* __restrict__ d2,
    const int* __restrict__ v1, const int* __restrict__ v2,
    const float* __restrict__ ls, const float* __restrict__ lsT,
    int* __restrict__ topkg, float* __restrict__ nwout)
{
    int L = blockIdx.x;
    int dir = blockIdx.y;
    const float* Ad = dir ? d2 : d1;
    const float* Bd = dir ? d1 : d2;
    const int* vA = dir ? v2 : v1;
    const int* vB = dir ? v1 : v2;
    const float* src = dir ? &lsT[(size_t)L * NL] : &ls[(size_t)L * NL];

    __shared__ float Asl[10 * 132];
    __shared__ float Bsl[10][1320];
    __shared__ float M[10][110];
    __shared__ int vam[10], tks[10];

    int tid = threadIdx.x;
    if (tid < 10) vam[tid] = vA[L * 10 + tid];
#pragma unroll
    for (int it = 0; it < 5; ++it) {
        int idx = tid + it * 256;
        int row = idx >> 7, col = idx & 127;
        Asl[row * 132 + col] = Ad[((size_t)L * 10 + row) * DD + col];
    }
    if (tid < 64) {
        int lane = tid;
        float v[8];
#pragma unroll
        for (int it = 0; it < 8; ++it) v[it] = src[it * 64 + lane];
        for (int p = 9; p >= 0; --p) {
            float bv = -3.0e38f;
            int bi_ = -1;
#pragma unroll
            for (int it = 0; it < 8; ++it) {
                int j = it * 64 + lane;
                bool better = (v[it] > bv) || (v[it] == bv && j > bi_);
                if (better) { bv = v[it]; bi_ = j; }
            }
#pragma unroll
            for (int m = 1; m < 64; m <<= 1) {
                float ov = __shfl_xor(bv, m);
                int oi = __shfl_xor(bi_, m);
                bool better = (ov > bv) || (ov == bv && oi > bi_);
                if (better) { bv = ov; bi_ = oi; }
            }
            if ((bi_ & 63) == lane) v[bi_ >> 6] = -3.0e38f;
            if (lane == 0) tks[p] = bi_;
        }
    }
    __syncthreads();
    if (tid < 10) topkg[(size_t)(dir * NL + L) * 10 + tid] = tks[tid];
#pragma unroll
    for (int it = 0; it < 50; ++it) {
        int idx = tid + it * 256;
        int c = idx / 1280;
        int rem = idx - c * 1280;
        int row = rem >> 7, col = rem & 127;
        Bsl[c][row * 132 + col] = Bd[((size_t)tks[c] * 10 + row) * DD + col];
    }
    __syncthreads();
#pragma unroll
    for (int it = 0; it < 4; ++it) {
        int w = tid + it * 256;
        if (w < 1000) {
            int c = w / 100;
            int rem = w - c * 100;
            int s = rem / 10, t = rem - s * 10;
            const float4* ap = (const float4*)&Asl[s * 132];
            const float4* bp = (const float4*)&Bsl[c][t * 132];
            float acc = 0.0f;
#pragma unroll
            for (int k = 0; k < 32; ++k) {
                float4 a = ap[k], b = bp[k];
                acc = fmaf(a.x, b.x, acc);
                acc = fmaf(a.y, b.y, acc);
                acc = fmaf(a.z, b.z, acc);
                acc = fmaf(a.w, b.w, acc);
            }
            int ok = vam[s] && vB[tks[c] * 10 + t];
            M[c][s * 11 + t] = ok ? acc : -1.0f;
        }
    }
    __syncthreads();

    if (tid < 20) {
        int c = tid % 10, f = tid / 10;
        float prev[11];
#pragma unroll
        for (int p = 0; p < 11; ++p) prev[p] = 0.0f;
#pragma unroll
        for (int s = 0; s < 10; ++s) {
            float oldp = prev[0];
            float run = -3.0e38f;
#pragma unroll
            for (int t = 0; t < 10; ++t) {
                int tt = f ? (9 - t) : t;
                float sc = M[c][s * 11 + tt] - 0.1f;
                float pt1 = prev[t + 1];
                float av = fmaxf(pt1, oldp + sc);
                run = fmaxf(run, av);
                prev[t + 1] = fmaxf(run, 0.0f);
                oldp = pt1;
            }
        }
        nwout[((size_t)(dir * NL + L)) * 20 + f * 10 + c] = prev[10];
    }
}

// ---------------- argmax + mutual check (separate dispatch) ----------------
__global__ __launch_bounds__(512) void final_kernel(
    const float* __restrict__ nw, const int* __restrict__ topk, int* __restrict__ out)
{
    __shared__ int m1[NL], m2[NL];
    int t = threadIdx.x;
    {
        const float* p = nw + (size_t)t * 20;
        float bb = -3.0e38f; int kk = 0;
        for (int k = 0; k < 20; ++k) {
            float v = p[k];
            if (v > bb) { bb = v; kk = k; }
        }
        m1[t] = topk[(size_t)t * 10 + (kk % 10)];
    }
    {
        const float* p = nw + (size_t)(NL + t) * 20;
        float bb = -3.0e38f; int kk = 0;
        for (int k = 0; k < 20; ++k) {
            float v = p[k];
            if (v > bb) { bb = v; kk = k; }
        }
        m2[t] = topk[(size_t)(NL + t) * 10 + (kk % 10)];
    }
    __syncthreads();
    int mt = m1[t];
    out[t] = (m2[mt] == t) ? mt : -1;
}

extern "C" void kernel_launch(void* const* d_in, const int* in_sizes, int n_in,
                              void* d_out, int out_size, void* d_ws, size_t ws_size,
                              hipStream_t stream)
{
    const float* seg1 = (const float*)d_in[0];
    const float* seg2 = (const float*)d_in[1];
    const float* desc1 = (const float*)d_in[2];
    const float* desc2 = (const float*)d_in[3];
    int* out = (int*)d_out;

    char* ws = (char*)d_ws;
    size_t off = 0;
    float* dt1 = (float*)(ws + off); off += (size_t)DD * HWC * 4;        // 8 MB
    float* dt2 = (float*)(ws + off); off += (size_t)DD * HWC * 4;        // 8 MB
    float* dd1 = (float*)(ws + off); off += (size_t)NL * SS * DD * 4;    // 2.5 MB
    float* dd2 = (float*)(ws + off); off += (size_t)NL * SS * DD * 4;    // 2.5 MB
    int* v1 = (int*)(ws + off); off += (size_t)NL * SS * 4;
    int* v2 = (int*)(ws + off); off += (size_t)NL * SS * 4;
    float* ls = (float*)(ws + off); off += (size_t)NL * NL * 4;          // 1 MB
    float* lsT = (float*)(ws + off); off += (size_t)NL * NL * 4;         // 1 MB
    int* topk = (int*)(ws + off); off += (size_t)2 * NL * 10 * 4;
    float* nwv = (float*)(ws + off); off += (size_t)2 * NL * 20 * 4;
    size_t PL = (size_t)NL * SS * DD;                                    // 655360 elems
    _Float16* h1 = (_Float16*)(ws + off); off += PL * 2;                 // 1.25 MB each
    _Float16* m1 = (_Float16*)(ws + off); off += PL * 2;
    _Float16* h2 = (_Float16*)(ws + off); off += PL * 2;
    _Float16* m2 = (_Float16*)(ws + off); off += PL * 2;

    transpose_kernel<<<dim3(HWC / 64, DD / 64, 2), 256, 0, stream>>>(
        desc1, desc2, dt1, dt2);
    sample_kernel<<<dim3(NL, 2), 640, 0, stream>>>(
        seg1, seg2, dt1, dt2, dd1, dd2, h1, m1, h2, m2, v1, v2);
    gemm_ls_kernel<<<1024, 256, 0, stream>>>(
        h1, m1, h2, m2, v1, v2, ls, lsT);
    nw_kernel<<<dim3(NL, 2), 256, 0, stream>>>(
        dd1, dd2, v1, v2, ls, lsT, topk, nwv);
    final_kernel<<<1, 512, 0, stream>>>(nwv, topk, out);
}